// Round 5
// baseline (15415.340 us; speedup 1.0000x reference)
//
#include <hip/hip_runtime.h>
#include <cstdint>
#include <cstddef>

#define T_STEPS 4096
#define IN_DIM  1088
#define H_DIM   2048
#define S_DIM   1024
#define G_DIM   (4*H_DIM)   // 8192
#define POISON  0xAAAAAAAAu

typedef __attribute__((ext_vector_type(8))) short short8;
typedef __attribute__((ext_vector_type(4))) float floatx4;

__device__ inline unsigned short f2bf(float f){
  unsigned u = __builtin_bit_cast(unsigned, f);
  unsigned r = (u + 0x7fffu + ((u >> 16) & 1u)) >> 16;
  return (unsigned short)r;
}
__device__ inline float bfu(unsigned short u){ return __builtin_bit_cast(float, (unsigned)u << 16); }

// fast transcendentals for the scan's critical tail:
// v_rcp_f32 is <=1 ulp; absmax headroom is ~10x, and the LSTM recurrence is
// contractive (f<1), so per-step 1e-7 perturbations don't accumulate.
__device__ inline float fast_rcp(float x){ return __builtin_amdgcn_rcpf(x); }
__device__ inline float fast_sig(float x){ return fast_rcp(1.f + __expf(-x)); }
__device__ inline float fast_tanh(float x){ return 1.f - 2.f * fast_rcp(1.f + __expf(2.f * x)); }

__global__ __launch_bounds__(256) void bias_sum(const float* __restrict__ a,
                                                const float* __restrict__ b,
                                                float* __restrict__ o){
  int i = blockIdx.x * 256 + threadIdx.x;
  o[i] = a[i] + b[i];
}

// ---------------- emulated-fp32 GEMM via bf16x3 MFMA ----------------
// C[M,N] = A[M,K] (fp32) * B[N,K]^T (fp32) + bias[N], out fp32 with ldC.
__global__ __launch_bounds__(256, 2) void gemm32x3_bt(const float* __restrict__ A,
                                                      const float* __restrict__ B,
                                                      const float* __restrict__ bias,
                                                      float* __restrict__ C,
                                                      int M, int N, int K, int ldC){
  __shared__ unsigned short lAh[128 * 64];
  __shared__ unsigned short lAl[128 * 64];
  __shared__ unsigned short lBh[128 * 64];
  __shared__ unsigned short lBl[128 * 64];
  const int n0 = blockIdx.x * 128, m0 = blockIdx.y * 128;
  const int tid = threadIdx.x;
  const int w = tid >> 6, lane = tid & 63;
  const int wm = (w >> 1) * 64, wn = (w & 1) * 64;
  const int srow = tid >> 1, shalf = tid & 1;

  floatx4 acc[4][4];
#pragma unroll
  for (int i = 0; i < 4; i++)
#pragma unroll
    for (int j = 0; j < 4; j++) acc[i][j] = (floatx4){0.f, 0.f, 0.f, 0.f};

  for (int k0 = 0; k0 < K; k0 += 64){
    const float4* gA = (const float4*)(A + (size_t)(m0 + srow) * K + k0 + shalf * 32);
    const float4* gB = (const float4*)(B + (size_t)(n0 + srow) * K + k0 + shalf * 32);
    float4 a4[8], b4[8];
#pragma unroll
    for (int c = 0; c < 8; c++){ a4[c] = gA[c]; b4[c] = gB[c]; }
    __syncthreads();
#pragma unroll
    for (int c = 0; c < 4; c++){
      int chunk = shalf * 4 + c;
      int pch = chunk ^ (srow & 7);
      ushort4 ah, al, bh, bl;
      float4 v0 = a4[2*c], v1 = a4[2*c+1];
      ah.x = f2bf(v0.x); al.x = f2bf(v0.x - bfu(ah.x));
      ah.y = f2bf(v0.y); al.y = f2bf(v0.y - bfu(ah.y));
      ah.z = f2bf(v0.z); al.z = f2bf(v0.z - bfu(ah.z));
      ah.w = f2bf(v0.w); al.w = f2bf(v0.w - bfu(ah.w));
      ushort4 ah2, al2;
      ah2.x = f2bf(v1.x); al2.x = f2bf(v1.x - bfu(ah2.x));
      ah2.y = f2bf(v1.y); al2.y = f2bf(v1.y - bfu(ah2.y));
      ah2.z = f2bf(v1.z); al2.z = f2bf(v1.z - bfu(ah2.z));
      ah2.w = f2bf(v1.w); al2.w = f2bf(v1.w - bfu(ah2.w));
      *(ushort4*)&lAh[srow * 64 + pch * 8]     = ah;
      *(ushort4*)&lAh[srow * 64 + pch * 8 + 4] = ah2;
      *(ushort4*)&lAl[srow * 64 + pch * 8]     = al;
      *(ushort4*)&lAl[srow * 64 + pch * 8 + 4] = al2;
      float4 u0 = b4[2*c], u1 = b4[2*c+1];
      bh.x = f2bf(u0.x); bl.x = f2bf(u0.x - bfu(bh.x));
      bh.y = f2bf(u0.y); bl.y = f2bf(u0.y - bfu(bh.y));
      bh.z = f2bf(u0.z); bl.z = f2bf(u0.z - bfu(bh.z));
      bh.w = f2bf(u0.w); bl.w = f2bf(u0.w - bfu(bh.w));
      ushort4 bh2, bl2;
      bh2.x = f2bf(u1.x); bl2.x = f2bf(u1.x - bfu(bh2.x));
      bh2.y = f2bf(u1.y); bl2.y = f2bf(u1.y - bfu(bh2.y));
      bh2.z = f2bf(u1.z); bl2.z = f2bf(u1.z - bfu(bh2.z));
      bh2.w = f2bf(u1.w); bl2.w = f2bf(u1.w - bfu(bh2.w));
      *(ushort4*)&lBh[srow * 64 + pch * 8]     = bh;
      *(ushort4*)&lBh[srow * 64 + pch * 8 + 4] = bh2;
      *(ushort4*)&lBl[srow * 64 + pch * 8]     = bl;
      *(ushort4*)&lBl[srow * 64 + pch * 8 + 4] = bl2;
    }
    __syncthreads();
#pragma unroll
    for (int ks = 0; ks < 2; ks++){
      short8 afh[4], afl[4], bfh[4], bfl[4];
      int chunk = ks * 4 + (lane >> 4);
#pragma unroll
      for (int i = 0; i < 4; i++){
        int r  = wm + i * 16 + (lane & 15);
        int o  = r * 64 + (chunk ^ (r & 7)) * 8;
        afh[i] = *(const short8*)&lAh[o];
        afl[i] = *(const short8*)&lAl[o];
        int rn = wn + i * 16 + (lane & 15);
        int on = rn * 64 + (chunk ^ (rn & 7)) * 8;
        bfh[i] = *(const short8*)&lBh[on];
        bfl[i] = *(const short8*)&lBl[on];
      }
#pragma unroll
      for (int i = 0; i < 4; i++)
#pragma unroll
        for (int j = 0; j < 4; j++){
          acc[i][j] = __builtin_amdgcn_mfma_f32_16x16x32_bf16(afl[i], bfh[j], acc[i][j], 0, 0, 0);
          acc[i][j] = __builtin_amdgcn_mfma_f32_16x16x32_bf16(afh[i], bfl[j], acc[i][j], 0, 0, 0);
          acc[i][j] = __builtin_amdgcn_mfma_f32_16x16x32_bf16(afh[i], bfh[j], acc[i][j], 0, 0, 0);
        }
    }
  }
#pragma unroll
  for (int i = 0; i < 4; i++){
#pragma unroll
    for (int j = 0; j < 4; j++){
      int col = n0 + wn + j * 16 + (lane & 15);
      float bv = bias[col];
#pragma unroll
      for (int r = 0; r < 4; r++){
        int row = m0 + wm + i * 16 + (lane >> 4) * 4 + r;
        C[(size_t)row * ldC + col] = acc[i][j][r] + bv;
      }
    }
  }
}

// ---------------- persistent LSTM scan (fp32, flag-gate + speculative fetch) ----------------
// 256 WGs x 512 thr, co-resident (cooperative). Wave wv owns h-unit hidx=b*8+wv.
// Weights (128 fp32/thread) pinned in the unified RF via "+a" (R2: 22.6->14.3ms).
// R4 protocol (fire-and-forget producers, consumer sentinel-verify): 14.3->11.4ms.
// R5 changes:
//  (1) SPECULATIVE FETCH: the h[t-1] data loads are issued BEFORE the flag
//      poll. __syncthreads() drains vmcnt(0) before s_barrier, so the data
//      RT completes DURING the poll -- detect and fetch overlap instead of
//      serializing (~700-900 cy off the chain). Sentinel-verify (already
//      needed for R4's unordered flag) absorbs early-snapshot stragglers.
//  (2) fast gate math: tanh = 1-2*rcp(1+e^{2x}), sigmoid = rcp(1+e^{-x})
//      (v_rcp_f32, <=1ulp) -- removes 2 libm tanhf + 3 IEEE v_div sequences
//      from the post-reduce critical tail.
__global__ __launch_bounds__(512, 2) void lstm_scan(const float* __restrict__ Whh,
                                                    const float* __restrict__ gx,
                                                    float* __restrict__ hs,
                                                    int* __restrict__ flags){
  __shared__ float hsh[H_DIM];
  const int b = blockIdx.x;
  const int tid = threadIdx.x;
  const int wv = tid >> 6, lane = tid & 63;
  const int hidx = b * 8 + wv;

  // weights: gate j, chunk c: k = lane*4 + 256*c  (coalesced float4 loads)
  floatx4 w[32];
#pragma unroll
  for (int j = 0; j < 4; j++){
    const float* base = Whh + (size_t)(j * H_DIM + hidx) * H_DIM + lane * 4;
#pragma unroll
    for (int c = 0; c < 8; c++) w[j * 8 + c] = *(const floatx4*)(base + 256 * c);
  }
  // pin in accumulator registers of the unified RF (not rematerializable)
#pragma unroll
  for (int r = 0; r < 32; r++)
    asm volatile("" : "+a"(w[r][0]), "+a"(w[r][1]), "+a"(w[r][2]), "+a"(w[r][3]));

  unsigned* ush = (unsigned*)hs;
  float cst = 0.f;

  // gx for t=0 (steady-state prefetch is t+1 at top of step t)
  const float* gxr0 = gx + hidx;
  float g0 = gxr0[0], g1 = gxr0[H_DIM], g2 = gxr0[2 * H_DIM], g3 = gxr0[3 * H_DIM];

  for (int t = 0; t < T_STEPS; t++){
    // prefetch gx[t+1]; latency hides under the poll + broadcast + compute
    const int tn = (t + 1 < T_STEPS) ? t + 1 : t;
    const float* gxn = gx + (size_t)tn * G_DIM + hidx;
    float n0 = gxn[0], n1 = gxn[H_DIM], n2 = gxn[2 * H_DIM], n3 = gxn[3 * H_DIM];

    float d0 = 0.f, d1 = 0.f, d2 = 0.f, d3 = 0.f;
    if (t > 0){
      // (1) speculative issue of own 16B of h[t-1] -- BEFORE flag confirm.
      // The confirm-barrier's vmcnt(0) drain completes these during the poll.
      const unsigned long long* hb =
          (const unsigned long long*)(hs + (size_t)(t - 1) * H_DIM);
      unsigned long long q0 = __hip_atomic_load(hb + tid,       __ATOMIC_RELAXED, __HIP_MEMORY_SCOPE_AGENT);
      unsigned long long q1 = __hip_atomic_load(hb + tid + 512, __ATOMIC_RELAXED, __HIP_MEMORY_SCOPE_AGENT);

      if (wv == 0){
        // poll all 256 per-WG flags; 4 fully-coalesced stride-64 dword loads
        const int* fp = flags + lane;
        for (;;){
          int v0 = __hip_atomic_load(fp + 0,   __ATOMIC_RELAXED, __HIP_MEMORY_SCOPE_AGENT);
          int v1 = __hip_atomic_load(fp + 64,  __ATOMIC_RELAXED, __HIP_MEMORY_SCOPE_AGENT);
          int v2 = __hip_atomic_load(fp + 128, __ATOMIC_RELAXED, __HIP_MEMORY_SCOPE_AGENT);
          int v3 = __hip_atomic_load(fp + 192, __ATOMIC_RELAXED, __HIP_MEMORY_SCOPE_AGENT);
          bool ok = (v0 >= t) & (v1 >= t) & (v2 >= t) & (v3 >= t);
          if (__all(ok)) break;
        }
      }
      __syncthreads();   // flags confirmed; LDS-reuse guard; q0/q1 landed

      // sentinel-VERIFY the speculative snapshot (rare per-dword retry)
      while (((unsigned)q0 == POISON) | ((unsigned)(q0 >> 32) == POISON))
        q0 = __hip_atomic_load(hb + tid,       __ATOMIC_RELAXED, __HIP_MEMORY_SCOPE_AGENT);
      while (((unsigned)q1 == POISON) | ((unsigned)(q1 >> 32) == POISON))
        q1 = __hip_atomic_load(hb + tid + 512, __ATOMIC_RELAXED, __HIP_MEMORY_SCOPE_AGENT);
      ((unsigned long long*)hsh)[tid]       = q0;
      ((unsigned long long*)hsh)[tid + 512] = q1;
      __syncthreads();   // staged

      const floatx4* hl = (const floatx4*)hsh + lane;   // + 64*c per chunk
#pragma unroll
      for (int c = 0; c < 8; c++){
        floatx4 h4 = hl[64 * c];            // b128, stride 16B/lane: conflict-free
        d0 = fmaf(w[c][0], h4[0], d0);      d0 = fmaf(w[c][1], h4[1], d0);
        d0 = fmaf(w[c][2], h4[2], d0);      d0 = fmaf(w[c][3], h4[3], d0);
        d1 = fmaf(w[8+c][0], h4[0], d1);    d1 = fmaf(w[8+c][1], h4[1], d1);
        d1 = fmaf(w[8+c][2], h4[2], d1);    d1 = fmaf(w[8+c][3], h4[3], d1);
        d2 = fmaf(w[16+c][0], h4[0], d2);   d2 = fmaf(w[16+c][1], h4[1], d2);
        d2 = fmaf(w[16+c][2], h4[2], d2);   d2 = fmaf(w[16+c][3], h4[3], d2);
        d3 = fmaf(w[24+c][0], h4[0], d3);   d3 = fmaf(w[24+c][1], h4[1], d3);
        d3 = fmaf(w[24+c][2], h4[2], d3);   d3 = fmaf(w[24+c][3], h4[3], d3);
      }
      // no post-FMA barrier: next iteration's confirm-barrier guards LDS reuse
    }
#pragma unroll
    for (int off = 32; off >= 1; off >>= 1){
      d0 += __shfl_xor(d0, off);
      d1 += __shfl_xor(d1, off);
      d2 += __shfl_xor(d2, off);
      d3 += __shfl_xor(d3, off);
    }
    float gi = g0 + d0, gf = g1 + d1, gg = g2 + d2, go = g3 + d3;
    float is = fast_sig(gi);
    float fs = fast_sig(gf);
    float gt = fast_tanh(gg);
    float os = fast_sig(go);
    cst = fs * cst + is * gt;               // identical across all 64 lanes
    float h = os * fast_tanh(cst);
    if (lane == 0){
      unsigned ub = __builtin_bit_cast(unsigned, h);
      if (ub == POISON) ub ^= 1u;           // dodge sentinel (2^-23 rel, harmless)
      __hip_atomic_store(ush + (size_t)t * H_DIM + hidx, ub,
                         __ATOMIC_RELAXED, __HIP_MEMORY_SCOPE_AGENT);
    }
    // fire-and-forget flag: no drain, no barrier; consumers sentinel-verify data
    if (tid == 0)
      __hip_atomic_store(flags + b, t + 1, __ATOMIC_RELAXED, __HIP_MEMORY_SCOPE_AGENT);
    g0 = n0; g1 = n1; g2 = n2; g3 = n3;
  }
}

// ---------------- softmax over rows of [T, S] ----------------
__global__ __launch_bounds__(256) void softmax_k(const float* __restrict__ logits,
                                                 float* __restrict__ out){
  const int row = blockIdx.x * 4 + (threadIdx.x >> 6);
  const int lane = threadIdx.x & 63;
  const float4* in = (const float4*)(logits + (size_t)row * S_DIM);
  float4* op = (float4*)(out + (size_t)row * S_DIM);
  float4 v[4];
  float m = -1e30f;
#pragma unroll
  for (int c = 0; c < 4; c++){
    v[c] = in[lane + 64 * c];
    m = fmaxf(m, fmaxf(fmaxf(v[c].x, v[c].y), fmaxf(v[c].z, v[c].w)));
  }
#pragma unroll
  for (int off = 32; off >= 1; off >>= 1) m = fmaxf(m, __shfl_xor(m, off));
  float s = 0.f;
#pragma unroll
  for (int c = 0; c < 4; c++){
    v[c].x = __expf(v[c].x - m); v[c].y = __expf(v[c].y - m);
    v[c].z = __expf(v[c].z - m); v[c].w = __expf(v[c].w - m);
    s += v[c].x + v[c].y + v[c].z + v[c].w;
  }
#pragma unroll
  for (int off = 32; off >= 1; off >>= 1) s += __shfl_xor(s, off);
  float inv = 1.f / s;
#pragma unroll
  for (int c = 0; c < 4; c++){
    v[c].x *= inv; v[c].y *= inv; v[c].z *= inv; v[c].w *= inv;
    op[lane + 64 * c] = v[c];
  }
}

extern "C" void kernel_launch(void* const* d_in, const int* in_sizes, int n_in,
                              void* d_out, int out_size, void* d_ws, size_t ws_size,
                              hipStream_t stream){
  const float* inputs  = (const float*)d_in[0];
  const float* W_embed = (const float*)d_in[1];
  const float* b_embed = (const float*)d_in[2];
  const float* W_ih    = (const float*)d_in[3];
  const float* b_ih    = (const float*)d_in[4];
  const float* W_hh    = (const float*)d_in[5];
  const float* b_hh    = (const float*)d_in[6];
  const float* W_out   = (const float*)d_in[7];
  const float* b_out   = (const float*)d_in[8];

  // ---- workspace layout: ~168 MB (proven safe) ----
  char* ws = (char*)d_ws;
  size_t off = 0;
  auto alloc = [&](size_t bytes) -> char* {
    char* p = ws + off;
    off = (off + bytes + 255) & ~(size_t)255;
    return p;
  };
  float* gx    = (float*)alloc((size_t)T_STEPS * G_DIM * 4);   // 134.2 MB [GEMM2 -> scan]
  float* x_hs  = (float*)alloc((size_t)T_STEPS * H_DIM * 4);   // 33.6 MB: x [G1->G2], then hs [scan->G3]
  float* biasg = (float*)alloc((size_t)G_DIM * 4);             // 32 KB
  int*   flags = (int*)alloc(256 * sizeof(int));               // 1 KB per-WG step flags
  float* logits = gx;                                          // alias: gx dead after scan

  bias_sum<<<G_DIM / 256, 256, 0, stream>>>(b_ih, b_hh, biasg);

  // GEMM1: x = inputs @ W_embed^T + b_embed
  gemm32x3_bt<<<dim3(H_DIM / 128, T_STEPS / 128), 256, 0, stream>>>(
      inputs, W_embed, b_embed, x_hs, T_STEPS, H_DIM, IN_DIM, H_DIM);

  // GEMM2: gx = x @ W_ih^T + (b_ih + b_hh)
  gemm32x3_bt<<<dim3(G_DIM / 128, T_STEPS / 128), 256, 0, stream>>>(
      x_hs, W_ih, biasg, gx, T_STEPS, G_DIM, H_DIM, G_DIM);

  // poison hs (x dead after GEMM2) -- consumer-side sentinel; re-runs every replay
  hipMemsetAsync(x_hs, 0xAA, (size_t)T_STEPS * H_DIM * 4, stream);
  // reset per-WG step flags
  hipMemsetAsync(flags, 0, 256 * sizeof(int), stream);

  // persistent scan (cooperative => all 256 WGs co-resident)
  const float* a0 = W_hh;
  const float* a1 = gx;
  float* a2 = x_hs;
  int* a3 = flags;
  void* args[] = { (void*)&a0, (void*)&a1, (void*)&a2, (void*)&a3 };
  hipLaunchCooperativeKernel((void*)lstm_scan, dim3(256), dim3(512), args, 0, stream);

  // GEMM3: logits = hs @ W_out^T + b_out   (logits alias gx region)
  gemm32x3_bt<<<dim3(S_DIM / 128, T_STEPS / 128), 256, 0, stream>>>(
      x_hs, W_out, b_out, logits, T_STEPS, S_DIM, H_DIM, S_DIM);

  softmax_k<<<T_STEPS / 4, 256, 0, stream>>>(logits, (float*)d_out);
}

// Round 6
// 12584.259 us; speedup vs baseline: 1.2250x; 1.2250x over previous
//
#include <hip/hip_runtime.h>
#include <cstdint>
#include <cstddef>

#define T_STEPS 4096
#define IN_DIM  1088
#define H_DIM   2048
#define S_DIM   1024
#define G_DIM   (4*H_DIM)   // 8192
#define POISON  0xAAAAAAAAu

typedef __attribute__((ext_vector_type(8))) short short8;
typedef __attribute__((ext_vector_type(4))) float floatx4;

__device__ inline unsigned short f2bf(float f){
  unsigned u = __builtin_bit_cast(unsigned, f);
  unsigned r = (u + 0x7fffu + ((u >> 16) & 1u)) >> 16;
  return (unsigned short)r;
}
__device__ inline float bfu(unsigned short u){ return __builtin_bit_cast(float, (unsigned)u << 16); }

// fast transcendentals (v_rcp_f32 <=1ulp; verified R5: absmax unchanged 7.6e-6)
__device__ inline float fast_rcp(float x){ return __builtin_amdgcn_rcpf(x); }
__device__ inline float fast_sig(float x){ return fast_rcp(1.f + __expf(-x)); }
__device__ inline float fast_tanh(float x){ return 1.f - 2.f * fast_rcp(1.f + __expf(2.f * x)); }

__global__ __launch_bounds__(256) void bias_sum(const float* __restrict__ a,
                                                const float* __restrict__ b,
                                                float* __restrict__ o){
  int i = blockIdx.x * 256 + threadIdx.x;
  o[i] = a[i] + b[i];
}

// ---------------- emulated-fp32 GEMM via bf16x3 MFMA ----------------
// C[M,N] = A[M,K] (fp32) * B[N,K]^T (fp32) + bias[N], out fp32 with ldC.
__global__ __launch_bounds__(256, 2) void gemm32x3_bt(const float* __restrict__ A,
                                                      const float* __restrict__ B,
                                                      const float* __restrict__ bias,
                                                      float* __restrict__ C,
                                                      int M, int N, int K, int ldC){
  __shared__ unsigned short lAh[128 * 64];
  __shared__ unsigned short lAl[128 * 64];
  __shared__ unsigned short lBh[128 * 64];
  __shared__ unsigned short lBl[128 * 64];
  const int n0 = blockIdx.x * 128, m0 = blockIdx.y * 128;
  const int tid = threadIdx.x;
  const int w = tid >> 6, lane = tid & 63;
  const int wm = (w >> 1) * 64, wn = (w & 1) * 64;
  const int srow = tid >> 1, shalf = tid & 1;

  floatx4 acc[4][4];
#pragma unroll
  for (int i = 0; i < 4; i++)
#pragma unroll
    for (int j = 0; j < 4; j++) acc[i][j] = (floatx4){0.f, 0.f, 0.f, 0.f};

  for (int k0 = 0; k0 < K; k0 += 64){
    const float4* gA = (const float4*)(A + (size_t)(m0 + srow) * K + k0 + shalf * 32);
    const float4* gB = (const float4*)(B + (size_t)(n0 + srow) * K + k0 + shalf * 32);
    float4 a4[8], b4[8];
#pragma unroll
    for (int c = 0; c < 8; c++){ a4[c] = gA[c]; b4[c] = gB[c]; }
    __syncthreads();
#pragma unroll
    for (int c = 0; c < 4; c++){
      int chunk = shalf * 4 + c;
      int pch = chunk ^ (srow & 7);
      ushort4 ah, al, bh, bl;
      float4 v0 = a4[2*c], v1 = a4[2*c+1];
      ah.x = f2bf(v0.x); al.x = f2bf(v0.x - bfu(ah.x));
      ah.y = f2bf(v0.y); al.y = f2bf(v0.y - bfu(ah.y));
      ah.z = f2bf(v0.z); al.z = f2bf(v0.z - bfu(ah.z));
      ah.w = f2bf(v0.w); al.w = f2bf(v0.w - bfu(ah.w));
      ushort4 ah2, al2;
      ah2.x = f2bf(v1.x); al2.x = f2bf(v1.x - bfu(ah2.x));
      ah2.y = f2bf(v1.y); al2.y = f2bf(v1.y - bfu(ah2.y));
      ah2.z = f2bf(v1.z); al2.z = f2bf(v1.z - bfu(ah2.z));
      ah2.w = f2bf(v1.w); al2.w = f2bf(v1.w - bfu(ah2.w));
      *(ushort4*)&lAh[srow * 64 + pch * 8]     = ah;
      *(ushort4*)&lAh[srow * 64 + pch * 8 + 4] = ah2;
      *(ushort4*)&lAl[srow * 64 + pch * 8]     = al;
      *(ushort4*)&lAl[srow * 64 + pch * 8 + 4] = al2;
      float4 u0 = b4[2*c], u1 = b4[2*c+1];
      bh.x = f2bf(u0.x); bl.x = f2bf(u0.x - bfu(bh.x));
      bh.y = f2bf(u0.y); bl.y = f2bf(u0.y - bfu(bh.y));
      bh.z = f2bf(u0.z); bl.z = f2bf(u0.z - bfu(bh.z));
      bh.w = f2bf(u0.w); bl.w = f2bf(u0.w - bfu(bh.w));
      ushort4 bh2, bl2;
      bh2.x = f2bf(u1.x); bl2.x = f2bf(u1.x - bfu(bh2.x));
      bh2.y = f2bf(u1.y); bl2.y = f2bf(u1.y - bfu(bh2.y));
      bh2.z = f2bf(u1.z); bl2.z = f2bf(u1.z - bfu(bh2.z));
      bh2.w = f2bf(u1.w); bl2.w = f2bf(u1.w - bfu(bh2.w));
      *(ushort4*)&lBh[srow * 64 + pch * 8]     = bh;
      *(ushort4*)&lBh[srow * 64 + pch * 8 + 4] = bh2;
      *(ushort4*)&lBl[srow * 64 + pch * 8]     = bl;
      *(ushort4*)&lBl[srow * 64 + pch * 8 + 4] = bl2;
    }
    __syncthreads();
#pragma unroll
    for (int ks = 0; ks < 2; ks++){
      short8 afh[4], afl[4], bfh[4], bfl[4];
      int chunk = ks * 4 + (lane >> 4);
#pragma unroll
      for (int i = 0; i < 4; i++){
        int r  = wm + i * 16 + (lane & 15);
        int o  = r * 64 + (chunk ^ (r & 7)) * 8;
        afh[i] = *(const short8*)&lAh[o];
        afl[i] = *(const short8*)&lAl[o];
        int rn = wn + i * 16 + (lane & 15);
        int on = rn * 64 + (chunk ^ (rn & 7)) * 8;
        bfh[i] = *(const short8*)&lBh[on];
        bfl[i] = *(const short8*)&lBl[on];
      }
#pragma unroll
      for (int i = 0; i < 4; i++)
#pragma unroll
        for (int j = 0; j < 4; j++){
          acc[i][j] = __builtin_amdgcn_mfma_f32_16x16x32_bf16(afl[i], bfh[j], acc[i][j], 0, 0, 0);
          acc[i][j] = __builtin_amdgcn_mfma_f32_16x16x32_bf16(afh[i], bfl[j], acc[i][j], 0, 0, 0);
          acc[i][j] = __builtin_amdgcn_mfma_f32_16x16x32_bf16(afh[i], bfh[j], acc[i][j], 0, 0, 0);
        }
    }
  }
#pragma unroll
  for (int i = 0; i < 4; i++){
#pragma unroll
    for (int j = 0; j < 4; j++){
      int col = n0 + wn + j * 16 + (lane & 15);
      float bv = bias[col];
#pragma unroll
      for (int r = 0; r < 4; r++){
        int row = m0 + wm + i * 16 + (lane >> 4) * 4 + r;
        C[(size_t)row * ldC + col] = acc[i][j][r] + bv;
      }
    }
  }
}

// ---------------- persistent LSTM scan (R4 protocol + gx off the detect path) --------
// 256 WGs x 512 thr, co-resident (cooperative). Wave wv owns h-unit hidx=b*8+wv.
// Weights (128 fp32/thread) pinned in the unified RF via "+a" (R2: 22.6->14.3ms).
// R4 (fire-and-forget producers + flag-gate + consumer sentinel-verify): ->11.4ms.
// R5 lesson: speculative pre-poll data loads sample BEFORE producers store
// (lockstep arrival) -> verify storms, regression. Data loads stay post-barrier.
// R6 fix: the gx[t+1] prefetch used to be issued BEFORE the flag poll; vmcnt
// counts all outstanding VMEM, so the poll's first round waited on the ~900cy
// HBM-cold gx loads -- gx latency sat INSIDE the detect path. Now issued AFTER
// the post-barrier h-loads (h-loads are older in vmcnt order, so verify doesn't
// drain gx); gx latency hides under verify+stage+FMA+tail (~1500+cy).
__global__ __launch_bounds__(512, 2) void lstm_scan(const float* __restrict__ Whh,
                                                    const float* __restrict__ gx,
                                                    float* __restrict__ hs,
                                                    int* __restrict__ flags){
  __shared__ float hsh[H_DIM];
  const int b = blockIdx.x;
  const int tid = threadIdx.x;
  const int wv = tid >> 6, lane = tid & 63;
  const int hidx = b * 8 + wv;

  // weights: gate j, chunk c: k = lane*4 + 256*c  (coalesced float4 loads)
  floatx4 w[32];
#pragma unroll
  for (int j = 0; j < 4; j++){
    const float* base = Whh + (size_t)(j * H_DIM + hidx) * H_DIM + lane * 4;
#pragma unroll
    for (int c = 0; c < 8; c++) w[j * 8 + c] = *(const floatx4*)(base + 256 * c);
  }
  // pin in accumulator registers of the unified RF (not rematerializable)
#pragma unroll
  for (int r = 0; r < 32; r++)
    asm volatile("" : "+a"(w[r][0]), "+a"(w[r][1]), "+a"(w[r][2]), "+a"(w[r][3]));

  unsigned* ush = (unsigned*)hs;
  float cst = 0.f;

  // gx for t=0
  const float* gxr0 = gx + hidx;
  float g0 = gxr0[0], g1 = gxr0[H_DIM], g2 = gxr0[2 * H_DIM], g3 = gxr0[3 * H_DIM];

  for (int t = 0; t < T_STEPS; t++){
    const int tn = (t + 1 < T_STEPS) ? t + 1 : t;
    const float* gxn = gx + (size_t)tn * G_DIM + hidx;
    float n0, n1, n2, n3;

    float d0 = 0.f, d1 = 0.f, d2 = 0.f, d3 = 0.f;
    if (t > 0){
      if (wv == 0){
        // poll all 256 per-WG flags; 4 fully-coalesced stride-64 dword loads.
        // NO other VMEM outstanding -> each round waits only on the flag RT.
        const int* fp = flags + lane;
        for (;;){
          int v0 = __hip_atomic_load(fp + 0,   __ATOMIC_RELAXED, __HIP_MEMORY_SCOPE_AGENT);
          int v1 = __hip_atomic_load(fp + 64,  __ATOMIC_RELAXED, __HIP_MEMORY_SCOPE_AGENT);
          int v2 = __hip_atomic_load(fp + 128, __ATOMIC_RELAXED, __HIP_MEMORY_SCOPE_AGENT);
          int v3 = __hip_atomic_load(fp + 192, __ATOMIC_RELAXED, __HIP_MEMORY_SCOPE_AGENT);
          bool ok = (v0 >= t) & (v1 >= t) & (v2 >= t) & (v3 >= t);
          if (__all(ok)) break;
        }
      }
      __syncthreads();   // flags confirmed; LDS-reuse guard (prev FMA done)

      // one-shot load of own 16B of h[t-1] (post-barrier: data is flagged)
      const unsigned long long* hb =
          (const unsigned long long*)(hs + (size_t)(t - 1) * H_DIM);
      unsigned long long q0 = __hip_atomic_load(hb + tid,       __ATOMIC_RELAXED, __HIP_MEMORY_SCOPE_AGENT);
      unsigned long long q1 = __hip_atomic_load(hb + tid + 512, __ATOMIC_RELAXED, __HIP_MEMORY_SCOPE_AGENT);

      // gx[t+1] prefetch: issued AFTER the h loads (younger in vmcnt order, so
      // the verify's waitcnt on q0/q1 doesn't drain it); consumed at next
      // step's gates -- ~900cy HBM latency hides under verify+stage+FMA+tail.
      n0 = gxn[0]; n1 = gxn[H_DIM]; n2 = gxn[2 * H_DIM]; n3 = gxn[3 * H_DIM];

      // sentinel-VERIFY the snapshot (rare per-dword retry: straggler produce)
      while (((unsigned)q0 == POISON) | ((unsigned)(q0 >> 32) == POISON))
        q0 = __hip_atomic_load(hb + tid,       __ATOMIC_RELAXED, __HIP_MEMORY_SCOPE_AGENT);
      while (((unsigned)q1 == POISON) | ((unsigned)(q1 >> 32) == POISON))
        q1 = __hip_atomic_load(hb + tid + 512, __ATOMIC_RELAXED, __HIP_MEMORY_SCOPE_AGENT);
      ((unsigned long long*)hsh)[tid]       = q0;
      ((unsigned long long*)hsh)[tid + 512] = q1;
      __syncthreads();   // staged

      const floatx4* hl = (const floatx4*)hsh + lane;   // + 64*c per chunk
#pragma unroll
      for (int c = 0; c < 8; c++){
        floatx4 h4 = hl[64 * c];            // b128, stride 16B/lane: conflict-free
        d0 = fmaf(w[c][0], h4[0], d0);      d0 = fmaf(w[c][1], h4[1], d0);
        d0 = fmaf(w[c][2], h4[2], d0);      d0 = fmaf(w[c][3], h4[3], d0);
        d1 = fmaf(w[8+c][0], h4[0], d1);    d1 = fmaf(w[8+c][1], h4[1], d1);
        d1 = fmaf(w[8+c][2], h4[2], d1);    d1 = fmaf(w[8+c][3], h4[3], d1);
        d2 = fmaf(w[16+c][0], h4[0], d2);   d2 = fmaf(w[16+c][1], h4[1], d2);
        d2 = fmaf(w[16+c][2], h4[2], d2);   d2 = fmaf(w[16+c][3], h4[3], d2);
        d3 = fmaf(w[24+c][0], h4[0], d3);   d3 = fmaf(w[24+c][1], h4[1], d3);
        d3 = fmaf(w[24+c][2], h4[2], d3);   d3 = fmaf(w[24+c][3], h4[3], d3);
      }
      // no post-FMA barrier: next iteration's confirm-barrier guards LDS reuse
    } else {
      n0 = gxn[0]; n1 = gxn[H_DIM]; n2 = gxn[2 * H_DIM]; n3 = gxn[3 * H_DIM];
    }
#pragma unroll
    for (int off = 32; off >= 1; off >>= 1){
      d0 += __shfl_xor(d0, off);
      d1 += __shfl_xor(d1, off);
      d2 += __shfl_xor(d2, off);
      d3 += __shfl_xor(d3, off);
    }
    float gi = g0 + d0, gf = g1 + d1, gg = g2 + d2, go = g3 + d3;
    float is = fast_sig(gi);
    float fs = fast_sig(gf);
    float gt = fast_tanh(gg);
    float os = fast_sig(go);
    cst = fs * cst + is * gt;               // identical across all 64 lanes
    float h = os * fast_tanh(cst);
    if (lane == 0){
      unsigned ub = __builtin_bit_cast(unsigned, h);
      if (ub == POISON) ub ^= 1u;           // dodge sentinel (2^-23 rel, harmless)
      __hip_atomic_store(ush + (size_t)t * H_DIM + hidx, ub,
                         __ATOMIC_RELAXED, __HIP_MEMORY_SCOPE_AGENT);
    }
    // fire-and-forget flag: no drain, no barrier; consumers sentinel-verify data
    if (tid == 0)
      __hip_atomic_store(flags + b, t + 1, __ATOMIC_RELAXED, __HIP_MEMORY_SCOPE_AGENT);
    g0 = n0; g1 = n1; g2 = n2; g3 = n3;
  }
}

// ---------------- softmax over rows of [T, S] ----------------
__global__ __launch_bounds__(256) void softmax_k(const float* __restrict__ logits,
                                                 float* __restrict__ out){
  const int row = blockIdx.x * 4 + (threadIdx.x >> 6);
  const int lane = threadIdx.x & 63;
  const float4* in = (const float4*)(logits + (size_t)row * S_DIM);
  float4* op = (float4*)(out + (size_t)row * S_DIM);
  float4 v[4];
  float m = -1e30f;
#pragma unroll
  for (int c = 0; c < 4; c++){
    v[c] = in[lane + 64 * c];
    m = fmaxf(m, fmaxf(fmaxf(v[c].x, v[c].y), fmaxf(v[c].z, v[c].w)));
  }
#pragma unroll
  for (int off = 32; off >= 1; off >>= 1) m = fmaxf(m, __shfl_xor(m, off));
  float s = 0.f;
#pragma unroll
  for (int c = 0; c < 4; c++){
    v[c].x = __expf(v[c].x - m); v[c].y = __expf(v[c].y - m);
    v[c].z = __expf(v[c].z - m); v[c].w = __expf(v[c].w - m);
    s += v[c].x + v[c].y + v[c].z + v[c].w;
  }
#pragma unroll
  for (int off = 32; off >= 1; off >>= 1) s += __shfl_xor(s, off);
  float inv = 1.f / s;
#pragma unroll
  for (int c = 0; c < 4; c++){
    v[c].x *= inv; v[c].y *= inv; v[c].z *= inv; v[c].w *= inv;
    op[lane + 64 * c] = v[c];
  }
}

extern "C" void kernel_launch(void* const* d_in, const int* in_sizes, int n_in,
                              void* d_out, int out_size, void* d_ws, size_t ws_size,
                              hipStream_t stream){
  const float* inputs  = (const float*)d_in[0];
  const float* W_embed = (const float*)d_in[1];
  const float* b_embed = (const float*)d_in[2];
  const float* W_ih    = (const float*)d_in[3];
  const float* b_ih    = (const float*)d_in[4];
  const float* W_hh    = (const float*)d_in[5];
  const float* b_hh    = (const float*)d_in[6];
  const float* W_out   = (const float*)d_in[7];
  const float* b_out   = (const float*)d_in[8];

  // ---- workspace layout: ~168 MB (proven safe) ----
  char* ws = (char*)d_ws;
  size_t off = 0;
  auto alloc = [&](size_t bytes) -> char* {
    char* p = ws + off;
    off = (off + bytes + 255) & ~(size_t)255;
    return p;
  };
  float* gx    = (float*)alloc((size_t)T_STEPS * G_DIM * 4);   // 134.2 MB [GEMM2 -> scan]
  float* x_hs  = (float*)alloc((size_t)T_STEPS * H_DIM * 4);   // 33.6 MB: x [G1->G2], then hs [scan->G3]
  float* biasg = (float*)alloc((size_t)G_DIM * 4);             // 32 KB
  int*   flags = (int*)alloc(256 * sizeof(int));               // 1 KB per-WG step flags
  float* logits = gx;                                          // alias: gx dead after scan

  bias_sum<<<G_DIM / 256, 256, 0, stream>>>(b_ih, b_hh, biasg);

  // GEMM1: x = inputs @ W_embed^T + b_embed
  gemm32x3_bt<<<dim3(H_DIM / 128, T_STEPS / 128), 256, 0, stream>>>(
      inputs, W_embed, b_embed, x_hs, T_STEPS, H_DIM, IN_DIM, H_DIM);

  // GEMM2: gx = x @ W_ih^T + (b_ih + b_hh)
  gemm32x3_bt<<<dim3(G_DIM / 128, T_STEPS / 128), 256, 0, stream>>>(
      x_hs, W_ih, biasg, gx, T_STEPS, G_DIM, H_DIM, G_DIM);

  // poison hs (x dead after GEMM2) -- consumer-side sentinel; re-runs every replay
  hipMemsetAsync(x_hs, 0xAA, (size_t)T_STEPS * H_DIM * 4, stream);
  // reset per-WG step flags
  hipMemsetAsync(flags, 0, 256 * sizeof(int), stream);

  // persistent scan (cooperative => all 256 WGs co-resident)
  const float* a0 = W_hh;
  const float* a1 = gx;
  float* a2 = x_hs;
  int* a3 = flags;
  void* args[] = { (void*)&a0, (void*)&a1, (void*)&a2, (void*)&a3 };
  hipLaunchCooperativeKernel((void*)lstm_scan, dim3(256), dim3(512), args, 0, stream);

  // GEMM3: logits = hs @ W_out^T + b_out   (logits alias gx region)
  gemm32x3_bt<<<dim3(S_DIM / 128, T_STEPS / 128), 256, 0, stream>>>(
      x_hs, W_out, b_out, logits, T_STEPS, S_DIM, H_DIM, S_DIM);

  softmax_k<<<T_STEPS / 4, 256, 0, stream>>>(logits, (float*)d_out);
}

// Round 8
// 11850.656 us; speedup vs baseline: 1.3008x; 1.0619x over previous
//
#include <hip/hip_runtime.h>
#include <cstdint>
#include <cstddef>

#define T_STEPS 4096
#define IN_DIM  1088
#define H_DIM   2048
#define S_DIM   1024
#define G_DIM   (4*H_DIM)   // 8192
#define POISON  0xAAAAAAAAu

typedef __attribute__((ext_vector_type(8))) short short8;
typedef __attribute__((ext_vector_type(4))) float floatx4;

__device__ inline unsigned short f2bf(float f){
  unsigned u = __builtin_bit_cast(unsigned, f);
  unsigned r = (u + 0x7fffu + ((u >> 16) & 1u)) >> 16;
  return (unsigned short)r;
}
__device__ inline float bfu(unsigned short u){ return __builtin_bit_cast(float, (unsigned)u << 16); }

// fast transcendentals (v_rcp_f32 <=1ulp; verified R5/R6: absmax unchanged 7.6e-6)
__device__ inline float fast_rcp(float x){ return __builtin_amdgcn_rcpf(x); }
__device__ inline float fast_sig(float x){ return fast_rcp(1.f + __expf(-x)); }
__device__ inline float fast_tanh(float x){ return 1.f - 2.f * fast_rcp(1.f + __expf(2.f * x)); }

__global__ __launch_bounds__(256) void bias_sum(const float* __restrict__ a,
                                                const float* __restrict__ b,
                                                float* __restrict__ o){
  int i = blockIdx.x * 256 + threadIdx.x;
  o[i] = a[i] + b[i];
}

// ---------------- emulated-fp32 GEMM via bf16x3 MFMA ----------------
// C[M,N] = A[M,K] (fp32) * B[N,K]^T (fp32) + bias[N], out fp32 with ldC.
__global__ __launch_bounds__(256, 2) void gemm32x3_bt(const float* __restrict__ A,
                                                      const float* __restrict__ B,
                                                      const float* __restrict__ bias,
                                                      float* __restrict__ C,
                                                      int M, int N, int K, int ldC){
  __shared__ unsigned short lAh[128 * 64];
  __shared__ unsigned short lAl[128 * 64];
  __shared__ unsigned short lBh[128 * 64];
  __shared__ unsigned short lBl[128 * 64];
  const int n0 = blockIdx.x * 128, m0 = blockIdx.y * 128;
  const int tid = threadIdx.x;
  const int w = tid >> 6, lane = tid & 63;
  const int wm = (w >> 1) * 64, wn = (w & 1) * 64;
  const int srow = tid >> 1, shalf = tid & 1;

  floatx4 acc[4][4];
#pragma unroll
  for (int i = 0; i < 4; i++)
#pragma unroll
    for (int j = 0; j < 4; j++) acc[i][j] = (floatx4){0.f, 0.f, 0.f, 0.f};

  for (int k0 = 0; k0 < K; k0 += 64){
    const float4* gA = (const float4*)(A + (size_t)(m0 + srow) * K + k0 + shalf * 32);
    const float4* gB = (const float4*)(B + (size_t)(n0 + srow) * K + k0 + shalf * 32);
    float4 a4[8], b4[8];
#pragma unroll
    for (int c = 0; c < 8; c++){ a4[c] = gA[c]; b4[c] = gB[c]; }
    __syncthreads();
#pragma unroll
    for (int c = 0; c < 4; c++){
      int chunk = shalf * 4 + c;
      int pch = chunk ^ (srow & 7);
      ushort4 ah, al, bh, bl;
      float4 v0 = a4[2*c], v1 = a4[2*c+1];
      ah.x = f2bf(v0.x); al.x = f2bf(v0.x - bfu(ah.x));
      ah.y = f2bf(v0.y); al.y = f2bf(v0.y - bfu(ah.y));
      ah.z = f2bf(v0.z); al.z = f2bf(v0.z - bfu(ah.z));
      ah.w = f2bf(v0.w); al.w = f2bf(v0.w - bfu(ah.w));
      ushort4 ah2, al2;
      ah2.x = f2bf(v1.x); al2.x = f2bf(v1.x - bfu(ah2.x));
      ah2.y = f2bf(v1.y); al2.y = f2bf(v1.y - bfu(ah2.y));
      ah2.z = f2bf(v1.z); al2.z = f2bf(v1.z - bfu(ah2.z));
      ah2.w = f2bf(v1.w); al2.w = f2bf(v1.w - bfu(ah2.w));
      *(ushort4*)&lAh[srow * 64 + pch * 8]     = ah;
      *(ushort4*)&lAh[srow * 64 + pch * 8 + 4] = ah2;
      *(ushort4*)&lAl[srow * 64 + pch * 8]     = al;
      *(ushort4*)&lAl[srow * 64 + pch * 8 + 4] = al2;
      float4 u0 = b4[2*c], u1 = b4[2*c+1];
      bh.x = f2bf(u0.x); bl.x = f2bf(u0.x - bfu(bh.x));
      bh.y = f2bf(u0.y); bl.y = f2bf(u0.y - bfu(bh.y));
      bh.z = f2bf(u0.z); bl.z = f2bf(u0.z - bfu(bh.z));
      bh.w = f2bf(u0.w); bl.w = f2bf(u0.w - bfu(bh.w));
      ushort4 bh2, bl2;
      bh2.x = f2bf(u1.x); bl2.x = f2bf(u1.x - bfu(bh2.x));
      bh2.y = f2bf(u1.y); bl2.y = f2bf(u1.y - bfu(bh2.y));
      bh2.z = f2bf(u1.z); bl2.z = f2bf(u1.z - bfu(bh2.z));
      bh2.w = f2bf(u1.w); bl2.w = f2bf(u1.w - bfu(bh2.w));
      *(ushort4*)&lBh[srow * 64 + pch * 8]     = bh;
      *(ushort4*)&lBh[srow * 64 + pch * 8 + 4] = bh2;
      *(ushort4*)&lBl[srow * 64 + pch * 8]     = bl;
      *(ushort4*)&lBl[srow * 64 + pch * 8 + 4] = bl2;
    }
    __syncthreads();
#pragma unroll
    for (int ks = 0; ks < 2; ks++){
      short8 afh[4], afl[4], bfh[4], bfl[4];
      int chunk = ks * 4 + (lane >> 4);
#pragma unroll
      for (int i = 0; i < 4; i++){
        int r  = wm + i * 16 + (lane & 15);
        int o  = r * 64 + (chunk ^ (r & 7)) * 8;
        afh[i] = *(const short8*)&lAh[o];
        afl[i] = *(const short8*)&lAl[o];
        int rn = wn + i * 16 + (lane & 15);
        int on = rn * 64 + (chunk ^ (rn & 7)) * 8;
        bfh[i] = *(const short8*)&lBh[on];
        bfl[i] = *(const short8*)&lBl[on];
      }
#pragma unroll
      for (int i = 0; i < 4; i++)
#pragma unroll
        for (int j = 0; j < 4; j++){
          acc[i][j] = __builtin_amdgcn_mfma_f32_16x16x32_bf16(afl[i], bfh[j], acc[i][j], 0, 0, 0);
          acc[i][j] = __builtin_amdgcn_mfma_f32_16x16x32_bf16(afh[i], bfl[j], acc[i][j], 0, 0, 0);
          acc[i][j] = __builtin_amdgcn_mfma_f32_16x16x32_bf16(afh[i], bfh[j], acc[i][j], 0, 0, 0);
        }
    }
  }
#pragma unroll
  for (int i = 0; i < 4; i++){
#pragma unroll
    for (int j = 0; j < 4; j++){
      int col = n0 + wn + j * 16 + (lane & 15);
      float bv = bias[col];
#pragma unroll
      for (int r = 0; r < 4; r++){
        int row = m0 + wm + i * 16 + (lane >> 4) * 4 + r;
        C[(size_t)row * ldC + col] = acc[i][j][r] + bv;
      }
    }
  }
}

// ---------------- persistent LSTM scan (R4 protocol + drain-free barriers) ----------
// 256 WGs x 512 thr, co-resident (cooperative). Wave wv owns h-unit hidx=b*8+wv.
// Weights (128 fp32/thread) pinned in the unified RF via "+a" (R2: 22.6->14.3ms).
// R4 (fire-and-forget producers + flag-gate + sentinel-verify): ->11.4ms.
// R6 lesson: __syncthreads() drains vmcnt(0) -- ANY in-flight prefetch dies at
// the next barrier. gx issued just before barrier-2 stalled every wave ~900cy.
// R7: raw s_barrier with MINIMAL waits:
//   barrier-1 (flag confirm + LDS-reuse guard): NO waitcnt. Wave0's poll waits
//     are use-driven; other waves' prior-step ds_reads were consumed (lgkm
//     waited) before entry, so reuse is safe.
//   barrier-2 (stage visible): lgkmcnt(0) ONLY (ds_writes retired). VMEM stays
//     in flight across both barriers.
// gx[t+1] is issued right AFTER barrier-2: it completes under FMA+reduce+tail
// (~1000+cy), faces no drain, and is first used at next step's gates.
// Deadlock audit (R8 resubmit after infra failure): barrier arrival needs no
// memory drain; flag-before-straggler-store race is absorbed by sentinel-verify
// (producer h-stores are issued before that wave's next barrier-1; flag
// propagation is acyclic) -- all spin loops terminate.
__global__ __launch_bounds__(512, 2) void lstm_scan(const float* __restrict__ Whh,
                                                    const float* __restrict__ gx,
                                                    float* __restrict__ hs,
                                                    int* __restrict__ flags){
  __shared__ float hsh[H_DIM];
  const int b = blockIdx.x;
  const int tid = threadIdx.x;
  const int wv = tid >> 6, lane = tid & 63;
  const int hidx = b * 8 + wv;

  // weights: gate j, chunk c: k = lane*4 + 256*c  (coalesced float4 loads)
  floatx4 w[32];
#pragma unroll
  for (int j = 0; j < 4; j++){
    const float* base = Whh + (size_t)(j * H_DIM + hidx) * H_DIM + lane * 4;
#pragma unroll
    for (int c = 0; c < 8; c++) w[j * 8 + c] = *(const floatx4*)(base + 256 * c);
  }
  // pin in accumulator registers of the unified RF (not rematerializable)
#pragma unroll
  for (int r = 0; r < 32; r++)
    asm volatile("" : "+a"(w[r][0]), "+a"(w[r][1]), "+a"(w[r][2]), "+a"(w[r][3]));

  unsigned* ush = (unsigned*)hs;
  float cst = 0.f;

  // gx for t=0
  const float* gxr0 = gx + hidx;
  float g0 = gxr0[0], g1 = gxr0[H_DIM], g2 = gxr0[2 * H_DIM], g3 = gxr0[3 * H_DIM];

  for (int t = 0; t < T_STEPS; t++){
    const int tn = (t + 1 < T_STEPS) ? t + 1 : t;
    const float* gxn = gx + (size_t)tn * G_DIM + hidx;
    float n0, n1, n2, n3;

    float d0 = 0.f, d1 = 0.f, d2 = 0.f, d3 = 0.f;
    if (t > 0){
      if (wv == 0){
        // poll all 256 per-WG flags; 4 fully-coalesced stride-64 dword loads.
        const int* fp = flags + lane;
        for (;;){
          int v0 = __hip_atomic_load(fp + 0,   __ATOMIC_RELAXED, __HIP_MEMORY_SCOPE_AGENT);
          int v1 = __hip_atomic_load(fp + 64,  __ATOMIC_RELAXED, __HIP_MEMORY_SCOPE_AGENT);
          int v2 = __hip_atomic_load(fp + 128, __ATOMIC_RELAXED, __HIP_MEMORY_SCOPE_AGENT);
          int v3 = __hip_atomic_load(fp + 192, __ATOMIC_RELAXED, __HIP_MEMORY_SCOPE_AGENT);
          bool ok = (v0 >= t) & (v1 >= t) & (v2 >= t) & (v3 >= t);
          if (__all(ok)) break;
        }
      }
      // barrier-1: raw, NO waitcnt drain (flag decision is control-flow;
      // prior-step LDS reads were consumed before entry)
      asm volatile("" ::: "memory");
      __builtin_amdgcn_s_barrier();
      asm volatile("" ::: "memory");

      // one-shot load of own 16B of h[t-1] (post-barrier: data is flagged)
      const unsigned long long* hb =
          (const unsigned long long*)(hs + (size_t)(t - 1) * H_DIM);
      unsigned long long q0 = __hip_atomic_load(hb + tid,       __ATOMIC_RELAXED, __HIP_MEMORY_SCOPE_AGENT);
      unsigned long long q1 = __hip_atomic_load(hb + tid + 512, __ATOMIC_RELAXED, __HIP_MEMORY_SCOPE_AGENT);

      // sentinel-VERIFY the snapshot (rare per-dword retry: straggler producer)
      while (((unsigned)q0 == POISON) | ((unsigned)(q0 >> 32) == POISON))
        q0 = __hip_atomic_load(hb + tid,       __ATOMIC_RELAXED, __HIP_MEMORY_SCOPE_AGENT);
      while (((unsigned)q1 == POISON) | ((unsigned)(q1 >> 32) == POISON))
        q1 = __hip_atomic_load(hb + tid + 512, __ATOMIC_RELAXED, __HIP_MEMORY_SCOPE_AGENT);
      ((unsigned long long*)hsh)[tid]       = q0;
      ((unsigned long long*)hsh)[tid + 512] = q1;

      // barrier-2: ds_writes retired (lgkmcnt(0)) -- but NO vmcnt drain, so
      // any in-flight VMEM survives the barrier
      asm volatile("s_waitcnt lgkmcnt(0)" ::: "memory");
      __builtin_amdgcn_s_barrier();
      asm volatile("" ::: "memory");

      // gx[t+1] prefetch: issued into the FMA+reduce+tail window (~1000+cy of
      // cover, no drain ahead); first use at next step's gates
      n0 = gxn[0]; n1 = gxn[H_DIM]; n2 = gxn[2 * H_DIM]; n3 = gxn[3 * H_DIM];

      const floatx4* hl = (const floatx4*)hsh + lane;   // + 64*c per chunk
#pragma unroll
      for (int c = 0; c < 8; c++){
        floatx4 h4 = hl[64 * c];            // b128, stride 16B/lane: conflict-free
        d0 = fmaf(w[c][0], h4[0], d0);      d0 = fmaf(w[c][1], h4[1], d0);
        d0 = fmaf(w[c][2], h4[2], d0);      d0 = fmaf(w[c][3], h4[3], d0);
        d1 = fmaf(w[8+c][0], h4[0], d1);    d1 = fmaf(w[8+c][1], h4[1], d1);
        d1 = fmaf(w[8+c][2], h4[2], d1);    d1 = fmaf(w[8+c][3], h4[3], d1);
        d2 = fmaf(w[16+c][0], h4[0], d2);   d2 = fmaf(w[16+c][1], h4[1], d2);
        d2 = fmaf(w[16+c][2], h4[2], d2);   d2 = fmaf(w[16+c][3], h4[3], d2);
        d3 = fmaf(w[24+c][0], h4[0], d3);   d3 = fmaf(w[24+c][1], h4[1], d3);
        d3 = fmaf(w[24+c][2], h4[2], d3);   d3 = fmaf(w[24+c][3], h4[3], d3);
      }
      // no post-FMA barrier: next iteration's barrier-1 guards LDS reuse
    } else {
      n0 = gxn[0]; n1 = gxn[H_DIM]; n2 = gxn[2 * H_DIM]; n3 = gxn[3 * H_DIM];
    }
#pragma unroll
    for (int off = 32; off >= 1; off >>= 1){
      d0 += __shfl_xor(d0, off);
      d1 += __shfl_xor(d1, off);
      d2 += __shfl_xor(d2, off);
      d3 += __shfl_xor(d3, off);
    }
    float gi = g0 + d0, gf = g1 + d1, gg = g2 + d2, go = g3 + d3;
    float is = fast_sig(gi);
    float fs = fast_sig(gf);
    float gt = fast_tanh(gg);
    float os = fast_sig(go);
    cst = fs * cst + is * gt;               // identical across all 64 lanes
    float h = os * fast_tanh(cst);
    if (lane == 0){
      unsigned ub = __builtin_bit_cast(unsigned, h);
      if (ub == POISON) ub ^= 1u;           // dodge sentinel (2^-23 rel, harmless)
      __hip_atomic_store(ush + (size_t)t * H_DIM + hidx, ub,
                         __ATOMIC_RELAXED, __HIP_MEMORY_SCOPE_AGENT);
    }
    // fire-and-forget flag: no drain, no barrier; consumers sentinel-verify data
    if (tid == 0)
      __hip_atomic_store(flags + b, t + 1, __ATOMIC_RELAXED, __HIP_MEMORY_SCOPE_AGENT);
    g0 = n0; g1 = n1; g2 = n2; g3 = n3;
  }
}

// ---------------- softmax over rows of [T, S] ----------------
__global__ __launch_bounds__(256) void softmax_k(const float* __restrict__ logits,
                                                 float* __restrict__ out){
  const int row = blockIdx.x * 4 + (threadIdx.x >> 6);
  const int lane = threadIdx.x & 63;
  const float4* in = (const float4*)(logits + (size_t)row * S_DIM);
  float4* op = (float4*)(out + (size_t)row * S_DIM);
  float4 v[4];
  float m = -1e30f;
#pragma unroll
  for (int c = 0; c < 4; c++){
    v[c] = in[lane + 64 * c];
    m = fmaxf(m, fmaxf(fmaxf(v[c].x, v[c].y), fmaxf(v[c].z, v[c].w)));
  }
#pragma unroll
  for (int off = 32; off >= 1; off >>= 1) m = fmaxf(m, __shfl_xor(m, off));
  float s = 0.f;
#pragma unroll
  for (int c = 0; c < 4; c++){
    v[c].x = __expf(v[c].x - m); v[c].y = __expf(v[c].y - m);
    v[c].z = __expf(v[c].z - m); v[c].w = __expf(v[c].w - m);
    s += v[c].x + v[c].y + v[c].z + v[c].w;
  }
#pragma unroll
  for (int off = 32; off >= 1; off >>= 1) s += __shfl_xor(s, off);
  float inv = 1.f / s;
#pragma unroll
  for (int c = 0; c < 4; c++){
    v[c].x *= inv; v[c].y *= inv; v[c].z *= inv; v[c].w *= inv;
    op[lane + 64 * c] = v[c];
  }
}

extern "C" void kernel_launch(void* const* d_in, const int* in_sizes, int n_in,
                              void* d_out, int out_size, void* d_ws, size_t ws_size,
                              hipStream_t stream){
  const float* inputs  = (const float*)d_in[0];
  const float* W_embed = (const float*)d_in[1];
  const float* b_embed = (const float*)d_in[2];
  const float* W_ih    = (const float*)d_in[3];
  const float* b_ih    = (const float*)d_in[4];
  const float* W_hh    = (const float*)d_in[5];
  const float* b_hh    = (const float*)d_in[6];
  const float* W_out   = (const float*)d_in[7];
  const float* b_out   = (const float*)d_in[8];

  // ---- workspace layout: ~168 MB (proven safe) ----
  char* ws = (char*)d_ws;
  size_t off = 0;
  auto alloc = [&](size_t bytes) -> char* {
    char* p = ws + off;
    off = (off + bytes + 255) & ~(size_t)255;
    return p;
  };
  float* gx    = (float*)alloc((size_t)T_STEPS * G_DIM * 4);   // 134.2 MB [GEMM2 -> scan]
  float* x_hs  = (float*)alloc((size_t)T_STEPS * H_DIM * 4);   // 33.6 MB: x [G1->G2], then hs [scan->G3]
  float* biasg = (float*)alloc((size_t)G_DIM * 4);             // 32 KB
  int*   flags = (int*)alloc(256 * sizeof(int));               // 1 KB per-WG step flags
  float* logits = gx;                                          // alias: gx dead after scan

  bias_sum<<<G_DIM / 256, 256, 0, stream>>>(b_ih, b_hh, biasg);

  // GEMM1: x = inputs @ W_embed^T + b_embed
  gemm32x3_bt<<<dim3(H_DIM / 128, T_STEPS / 128), 256, 0, stream>>>(
      inputs, W_embed, b_embed, x_hs, T_STEPS, H_DIM, IN_DIM, H_DIM);

  // GEMM2: gx = x @ W_ih^T + (b_ih + b_hh)
  gemm32x3_bt<<<dim3(G_DIM / 128, T_STEPS / 128), 256, 0, stream>>>(
      x_hs, W_ih, biasg, gx, T_STEPS, G_DIM, H_DIM, G_DIM);

  // poison hs (x dead after GEMM2) -- consumer-side sentinel; re-runs every replay
  hipMemsetAsync(x_hs, 0xAA, (size_t)T_STEPS * H_DIM * 4, stream);
  // reset per-WG step flags
  hipMemsetAsync(flags, 0, 256 * sizeof(int), stream);

  // persistent scan (cooperative => all 256 WGs co-resident)
  const float* a0 = W_hh;
  const float* a1 = gx;
  float* a2 = x_hs;
  int* a3 = flags;
  void* args[] = { (void*)&a0, (void*)&a1, (void*)&a2, (void*)&a3 };
  hipLaunchCooperativeKernel((void*)lstm_scan, dim3(256), dim3(512), args, 0, stream);

  // GEMM3: logits = hs @ W_out^T + b_out   (logits alias gx region)
  gemm32x3_bt<<<dim3(S_DIM / 128, T_STEPS / 128), 256, 0, stream>>>(
      x_hs, W_out, b_out, logits, T_STEPS, S_DIM, H_DIM, S_DIM);

  softmax_k<<<T_STEPS / 4, 256, 0, stream>>>(logits, (float*)d_out);
}